// Round 1
// baseline (1936.585 us; speedup 1.0000x reference)
//
#include <hip/hip_runtime.h>
#include <math.h>

// ---------------- problem constants ----------------
constexpr int kB = 4, kW = 2000, kI = 64, kS = 64, kT = 24, kU = 32, kUS = 2;
constexpr int kPER = kW + kI + kS + kU + 1;   // 2161 nodes per graph
constexpr int kN   = kB * kPER;               // 8644 nodes total
constexpr int kTxtPer  = kW + kS + kU + 1;    // 2097 text rows per graph
constexpr int kTxtRows = kB * kTxtPer;        // 8388 text rows
constexpr int kEmb = 300;
constexpr int kHid = 1024;                    // H*D for gat0/gat1
constexpr int kOut = 512;

// ---------------- feature construction ----------------

__global__ void k_sent(const int* __restrict__ sents, const float* __restrict__ smask,
                       const float* __restrict__ wemb, float* __restrict__ sent) {
  int bs = blockIdx.x;                 // 0..B*S-1
  __shared__ int idx[kT];
  __shared__ float mk[kT];
  __shared__ float s_cnt;
  int t = threadIdx.x;
  if (t < kT) { idx[t] = sents[bs * kT + t]; mk[t] = smask[bs * kT + t]; }
  __syncthreads();
  if (t == 0) {
    float c = 0.f;
    for (int i = 0; i < kT; ++i) c += mk[i];
    s_cnt = (c == 0.f) ? 1.f : c;
  }
  __syncthreads();
  for (int d = t; d < kEmb; d += blockDim.x) {
    float acc = 0.f;
    for (int i = 0; i < kT; ++i) acc += wemb[idx[i] * kEmb + d] * mk[i];
    sent[bs * kEmb + d] = acc / s_cnt;
  }
}

__global__ void k_utt(const int* __restrict__ utts, const float* __restrict__ umask,
                      const float* __restrict__ sent, float* __restrict__ utt) {
  int bu = blockIdx.x;                 // 0..B*U-1
  int b = bu / kU;
  __shared__ int idx[kUS];
  __shared__ float mk[kUS];
  __shared__ float s_cnt;
  int t = threadIdx.x;
  if (t < kUS) { idx[t] = utts[bu * kUS + t]; mk[t] = umask[bu * kUS + t]; }
  __syncthreads();
  if (t == 0) {
    float c = 0.f;
    for (int i = 0; i < kUS; ++i) c += mk[i];
    s_cnt = (c == 0.f) ? 1.f : c;
  }
  __syncthreads();
  for (int d = t; d < kEmb; d += blockDim.x) {
    float acc = 0.f;
    for (int i = 0; i < kUS; ++i) acc += sent[(b * kS + idx[i]) * kEmb + d] * mk[i];
    utt[bu * kEmb + d] = acc / s_cnt;
  }
}

__global__ void k_sess(const float* __restrict__ utt, float* __restrict__ sess) {
  int b = blockIdx.x;
  for (int d = threadIdx.x; d < kEmb; d += blockDim.x) {
    float acc = 0.f;
    for (int u = 0; u < kU; ++u) acc += utt[(b * kU + u) * kEmb + d];
    sess[b * kEmb + d] = acc * (1.f / kU);
  }
}

__global__ void k_txtgather(const int* __restrict__ aw, const float* __restrict__ wemb,
                            const float* __restrict__ sent, const float* __restrict__ utt,
                            const float* __restrict__ sess, float* __restrict__ txt) {
  int r = blockIdx.x;                  // 0..kTxtRows-1
  int g = r / kTxtPer, j = r - g * kTxtPer;
  const float* src;
  if (j < kW)                 src = wemb + (size_t)aw[g * kW + j] * kEmb;
  else if (j < kW + kS)       src = sent + (size_t)(g * kS + (j - kW)) * kEmb;
  else if (j < kW + kS + kU)  src = utt  + (size_t)(g * kU + (j - kW - kS)) * kEmb;
  else                        src = sess + (size_t)g * kEmb;
  for (int d = threadIdx.x; d < kEmb; d += blockDim.x) txt[(size_t)r * kEmb + d] = src[d];
}

__global__ void k_rowmap(int* __restrict__ rt, int* __restrict__ ri) {
  int i = blockIdx.x * blockDim.x + threadIdx.x;
  if (i < kTxtRows) {
    int g = i / kTxtPer, j = i - g * kTxtPer;
    int base = g * kPER;
    int node;
    if (j < kW)                 node = base + j;
    else if (j < kW + kS)       node = base + kW + kI + (j - kW);
    else if (j < kW + kS + kU)  node = base + kW + kI + kS + (j - kW - kS);
    else                        node = base + kW + kI + kS + kU;
    rt[i] = node;
  }
  if (i < kB * kI) {
    int g = i >> 6;
    ri[i] = g * kPER + kW + (i & 63);
  }
}

// ---------------- tiled fp32 GEMM: C[rmap[r]] = A[r,:K] @ Bm[:K,:Nc] (+bias) ----------------
#define BM 64
#define BN 64
#define BK 16
__global__ __launch_bounds__(256) void k_gemm(const float* __restrict__ A,
                                              const float* __restrict__ Bm,
                                              const float* __restrict__ bias,
                                              const int* __restrict__ rmap,
                                              float* __restrict__ C,
                                              int M, int K, int Nc) {
  __shared__ float As[BK][BM + 1];
  __shared__ float Bs[BK][BN];
  int tid = threadIdx.x;
  int tm = tid >> 4, tn = tid & 15;
  int row0 = blockIdx.y * BM, col0 = blockIdx.x * BN;
  float acc[4][4] = {};
  for (int k0 = 0; k0 < K; k0 += BK) {
#pragma unroll
    for (int i = 0; i < 4; ++i) {
      int idx = tid + i * 256;
      int ar = idx >> 4, ac = idx & 15;
      int gr = row0 + ar, gc = k0 + ac;
      As[ac][ar] = (gr < M && gc < K) ? A[(size_t)gr * K + gc] : 0.f;
    }
#pragma unroll
    for (int i = 0; i < 4; ++i) {
      int idx = tid + i * 256;
      int br = idx >> 6, bc = idx & 63;
      int gr = k0 + br;
      Bs[br][bc] = (gr < K) ? Bm[(size_t)gr * Nc + col0 + bc] : 0.f;
    }
    __syncthreads();
#pragma unroll
    for (int k = 0; k < BK; ++k) {
      float av[4], bv[4];
#pragma unroll
      for (int i = 0; i < 4; ++i) av[i] = As[k][tm * 4 + i];
#pragma unroll
      for (int j = 0; j < 4; ++j) bv[j] = Bs[k][tn * 4 + j];
#pragma unroll
      for (int i = 0; i < 4; ++i)
#pragma unroll
        for (int j = 0; j < 4; ++j) acc[i][j] += av[i] * bv[j];
    }
    __syncthreads();
  }
#pragma unroll
  for (int i = 0; i < 4; ++i) {
    int r = row0 + tm * 4 + i;
    if (r >= M) continue;
    int orow = rmap ? rmap[r] : r;
#pragma unroll
    for (int j = 0; j < 4; ++j) {
      int c = col0 + tn * 4 + j;
      float v = acc[i][j];
      if (bias) v += bias[c];
      C[(size_t)orow * Nc + c] = v;
    }
  }
}

// ---------------- per-node attention logits: el/er = sum_d f[n,h,d]*a[h,d] ----------------
__global__ void k_elr(const float* __restrict__ f, const float* __restrict__ al,
                      const float* __restrict__ ar, float* __restrict__ el,
                      float* __restrict__ er, int H, int D) {
  int v = blockIdx.x;
  int tid = threadIdx.x;
  int wave = tid >> 6, lane = tid & 63;
  for (int h = wave; h < H; h += 4) {
    float a = 0.f, b = 0.f;
    for (int d = lane; d < D; d += 64) {
      float x = f[(size_t)v * H * D + h * D + d];
      a += x * al[h * D + d];
      b += x * ar[h * D + d];
    }
    for (int off = 32; off; off >>= 1) {
      a += __shfl_down(a, off);
      b += __shfl_down(b, off);
    }
    if (lane == 0) { el[v * H + h] = a; er[v * H + h] = b; }
  }
}

// ---------------- CSR build (group edges by dst) ----------------
__global__ void k_count(const int* __restrict__ dst, int* __restrict__ cnt, int E) {
  int e = blockIdx.x * blockDim.x + threadIdx.x;
  if (e < E) atomicAdd(&cnt[dst[e]], 1);
}

__global__ void k_scan(const int* __restrict__ deg, int* __restrict__ offs, int n) {
  __shared__ int part[1024];
  int tid = threadIdx.x;
  int per = (n + 1023) >> 10;
  int start = tid * per;
  int local = 0;
  for (int i = 0; i < per; ++i) { int idx = start + i; if (idx < n) local += deg[idx]; }
  part[tid] = local;
  __syncthreads();
  for (int off = 1; off < 1024; off <<= 1) {
    int add = (tid >= off) ? part[tid - off] : 0;
    __syncthreads();
    part[tid] += add;
    __syncthreads();
  }
  int run = (tid == 0) ? 0 : part[tid - 1];
  for (int i = 0; i < per; ++i) {
    int idx = start + i;
    if (idx < n) { offs[idx] = run; run += deg[idx]; }
  }
  if (tid == 1023) offs[n] = part[1023];
}

__global__ void k_fill(const int* __restrict__ src, const int* __restrict__ dst,
                       const int* __restrict__ offs, int* __restrict__ cur,
                       int* __restrict__ csr, int E) {
  int e = blockIdx.x * blockDim.x + threadIdx.x;
  if (e < E) {
    int d = dst[e];
    int slot = offs[d] + atomicAdd(&cur[d], 1);
    csr[slot] = src[e];
  }
}

// ---------------- GAT edge-softmax + aggregate, one block per dst node ----------------
template <int H, int D, int ACT>
__global__ __launch_bounds__(256) void k_agg(const float* __restrict__ f,
                                             const float* __restrict__ el,
                                             const float* __restrict__ er,
                                             const int* __restrict__ offs,
                                             const int* __restrict__ csr,
                                             const float* __restrict__ bias,
                                             float* __restrict__ out) {
  constexpr int HD = H * D;
  constexpr int K = HD / 256;
  int v = blockIdx.x;
  int tid = threadIdx.x;
  float erv[H];
#pragma unroll
  for (int h = 0; h < H; ++h) erv[h] = er[v * H + h];
  int e0 = offs[v], e1 = offs[v + 1];
  // pass 1: per-head max logit (every thread computes redundantly; reads broadcast)
  float m[H];
#pragma unroll
  for (int h = 0; h < H; ++h) m[h] = -1e30f;
  for (int e = e0; e < e1; ++e) {
    int s = csr[e];
#pragma unroll
    for (int h = 0; h < H; ++h) {
      float x = el[s * H + h] + erv[h];
      x = x > 0.f ? x : 0.2f * x;
      m[h] = fmaxf(m[h], x);
    }
  }
  // pass 2: weights + weighted gather of f[src]
  float z[H];
  float acc[K];
#pragma unroll
  for (int h = 0; h < H; ++h) z[h] = 0.f;
#pragma unroll
  for (int k = 0; k < K; ++k) acc[k] = 0.f;
  for (int e = e0; e < e1; ++e) {
    int s = csr[e];
    float w[H];
#pragma unroll
    for (int h = 0; h < H; ++h) {
      float x = el[s * H + h] + erv[h];
      x = x > 0.f ? x : 0.2f * x;
      w[h] = expf(x - m[h]);
      z[h] += w[h];
    }
#pragma unroll
    for (int k = 0; k < K; ++k) {
      int d = (k << 8) + tid;
      int h = d / D;
      acc[k] += w[h] * f[(size_t)s * HD + d];
    }
  }
#pragma unroll
  for (int k = 0; k < K; ++k) {
    int d = (k << 8) + tid;
    int h = d / D;
    float o = acc[k] / z[h] + bias[d];
    if (ACT) o = o > 0.f ? o : expm1f(o);
    out[(size_t)v * HD + d] = o;
  }
}

__global__ void k_outgather(const int* __restrict__ sid, const float* __restrict__ h,
                            float* __restrict__ out) {
  int b = blockIdx.x;
  for (int d = threadIdx.x; d < kOut; d += blockDim.x)
    out[b * kOut + d] = h[(size_t)sid[b] * kOut + d];
}

// ---------------- launcher ----------------
extern "C" void kernel_launch(void* const* d_in, const int* in_sizes, int n_in,
                              void* d_out, int out_size, void* d_ws, size_t ws_size,
                              hipStream_t stream) {
  const int*   all_words   = (const int*)d_in[0];
  const float* image_feats = (const float*)d_in[1];
  const int*   sentences   = (const int*)d_in[2];
  const float* sent_mask   = (const float*)d_in[3];
  const int*   utterances  = (const int*)d_in[4];
  const float* utt_mask    = (const float*)d_in[5];
  const int*   session_ids = (const int*)d_in[6];
  const int*   edge_src    = (const int*)d_in[7];
  const int*   edge_dst    = (const int*)d_in[8];
  const float* word_embed  = (const float*)d_in[9];
  const float* text_fc_w   = (const float*)d_in[10];
  const float* text_fc_b   = (const float*)d_in[11];
  const float* image_fc_w  = (const float*)d_in[12];
  const float* image_fc_b  = (const float*)d_in[13];
  const float* gat0_fc     = (const float*)d_in[14];
  const float* gat0_al     = (const float*)d_in[15];
  const float* gat0_ar     = (const float*)d_in[16];
  const float* gat0_b      = (const float*)d_in[17];
  const float* gat1_fc     = (const float*)d_in[18];
  const float* gat1_al     = (const float*)d_in[19];
  const float* gat1_ar     = (const float*)d_in[20];
  const float* gat1_b      = (const float*)d_in[21];
  const float* gat2_fc     = (const float*)d_in[22];
  const float* gat2_al     = (const float*)d_in[23];
  const float* gat2_ar     = (const float*)d_in[24];
  const float* gat2_b      = (const float*)d_in[25];

  const int E = in_sizes[7];

  // workspace layout
  char* base = (char*)d_ws;
  size_t off = 0;
  auto alloc = [&](size_t elems, size_t esz) -> void* {
    void* p = base + off;
    off += ((elems * esz + 255) / 256) * 256;
    return p;
  };
  float* hbuf   = (float*)alloc((size_t)kN * kHid, 4);
  float* fbuf   = (float*)alloc((size_t)kN * kHid, 4);
  float* sentb  = (float*)alloc((size_t)kB * kS * kEmb, 4);
  float* uttb   = (float*)alloc((size_t)kB * kU * kEmb, 4);
  float* sessb  = (float*)alloc((size_t)kB * kEmb, 4);
  float* txtin  = (float*)alloc((size_t)kTxtRows * kEmb, 4);
  float* el     = (float*)alloc((size_t)kN * 4, 4);
  float* er     = (float*)alloc((size_t)kN * 4, 4);
  int*   offs   = (int*)alloc(kN + 1, 4);
  int*   cnt    = (int*)alloc(kN, 4);
  int*   csr    = (int*)alloc(E, 4);
  int*   rmt    = (int*)alloc(kTxtRows, 4);
  int*   rmi    = (int*)alloc(kB * kI, 4);
  (void)ws_size; (void)n_in; (void)out_size;

  // --- feature construction ---
  k_sent<<<kB * kS, 128, 0, stream>>>(sentences, sent_mask, word_embed, sentb);
  k_utt<<<kB * kU, 128, 0, stream>>>(utterances, utt_mask, sentb, uttb);
  k_sess<<<kB, 128, 0, stream>>>(uttb, sessb);
  k_txtgather<<<kTxtRows, 128, 0, stream>>>(all_words, word_embed, sentb, uttb, sessb, txtin);
  k_rowmap<<<(kTxtRows + 255) / 256, 256, 0, stream>>>(rmt, rmi);

  // text FC: [8388,300] @ [300,1024] -> scattered into hbuf
  k_gemm<<<dim3(kHid / BN, (kTxtRows + BM - 1) / BM), 256, 0, stream>>>(
      txtin, text_fc_w, text_fc_b, rmt, hbuf, kTxtRows, kEmb, kHid);
  // image FC: [256,2048] @ [2048,1024] -> scattered into hbuf
  k_gemm<<<dim3(kHid / BN, (kB * kI + BM - 1) / BM), 256, 0, stream>>>(
      image_feats, image_fc_w, image_fc_b, rmi, hbuf, kB * kI, 2048, kHid);

  // --- CSR build ---
  hipMemsetAsync(cnt, 0, kN * sizeof(int), stream);
  k_count<<<(E + 255) / 256, 256, 0, stream>>>(edge_dst, cnt, E);
  k_scan<<<1, 1024, 0, stream>>>(cnt, offs, kN);
  hipMemsetAsync(cnt, 0, kN * sizeof(int), stream);
  k_fill<<<(E + 255) / 256, 256, 0, stream>>>(edge_src, edge_dst, offs, cnt, csr, E);

  // --- GAT layer 0 (1024 -> 4x256, ELU) ---
  k_gemm<<<dim3(kHid / BN, (kN + BM - 1) / BM), 256, 0, stream>>>(
      hbuf, gat0_fc, nullptr, nullptr, fbuf, kN, kHid, kHid);
  k_elr<<<kN, 256, 0, stream>>>(fbuf, gat0_al, gat0_ar, el, er, 4, 256);
  k_agg<4, 256, 1><<<kN, 256, 0, stream>>>(fbuf, el, er, offs, csr, gat0_b, hbuf);

  // --- GAT layer 1 (1024 -> 4x256, ELU) ---
  k_gemm<<<dim3(kHid / BN, (kN + BM - 1) / BM), 256, 0, stream>>>(
      hbuf, gat1_fc, nullptr, nullptr, fbuf, kN, kHid, kHid);
  k_elr<<<kN, 256, 0, stream>>>(fbuf, gat1_al, gat1_ar, el, er, 4, 256);
  k_agg<4, 256, 1><<<kN, 256, 0, stream>>>(fbuf, el, er, offs, csr, gat1_b, hbuf);

  // --- GAT layer 2 (1024 -> 1x512, no act) ---
  k_gemm<<<dim3(kOut / BN, (kN + BM - 1) / BM), 256, 0, stream>>>(
      hbuf, gat2_fc, nullptr, nullptr, fbuf, kN, kHid, kOut);
  k_elr<<<kN, 256, 0, stream>>>(fbuf, gat2_al, gat2_ar, el, er, 1, 512);
  k_agg<1, 512, 0><<<kN, 256, 0, stream>>>(fbuf, el, er, offs, csr, gat2_b, hbuf);

  // --- output gather ---
  k_outgather<<<kB, 256, 0, stream>>>(session_ids, hbuf, (float*)d_out);
}

// Round 2
// 695.387 us; speedup vs baseline: 2.7849x; 2.7849x over previous
//
#include <hip/hip_runtime.h>
#include <math.h>

// ---------------- problem constants ----------------
constexpr int kB = 4, kW = 2000, kI = 64, kS = 64, kT = 24, kU = 32, kUS = 2;
constexpr int kPER = kW + kI + kS + kU + 1;   // 2161 nodes per graph
constexpr int kN   = kB * kPER;               // 8644 nodes total
constexpr int kTxtPer  = kW + kS + kU + 1;    // 2097 text rows per graph
constexpr int kTxtRows = kB * kTxtPer;        // 8388 text rows
constexpr int kEmb = 300;
constexpr int kEmbPad = 320;                  // padded to multiple of 64 for MFMA K-loop
constexpr int kHid = 1024;
constexpr int kOut = 512;

typedef __attribute__((ext_vector_type(8))) short bf16x8;
typedef __attribute__((ext_vector_type(4))) float f32x4;

__device__ __forceinline__ unsigned short f2bf(float f) {
  union { float f; unsigned int u; } x; x.f = f;
  unsigned int r = x.u + 0x7FFF + ((x.u >> 16) & 1);
  return (unsigned short)(r >> 16);
}

// ---------------- feature construction (fp32) ----------------

__global__ void k_sent(const int* __restrict__ sents, const float* __restrict__ smask,
                       const float* __restrict__ wemb, float* __restrict__ sent) {
  int bs = blockIdx.x;
  __shared__ int idx[kT];
  __shared__ float mk[kT];
  __shared__ float s_cnt;
  int t = threadIdx.x;
  if (t < kT) { idx[t] = sents[bs * kT + t]; mk[t] = smask[bs * kT + t]; }
  __syncthreads();
  if (t == 0) {
    float c = 0.f;
    for (int i = 0; i < kT; ++i) c += mk[i];
    s_cnt = (c == 0.f) ? 1.f : c;
  }
  __syncthreads();
  for (int d = t; d < kEmb; d += blockDim.x) {
    float acc = 0.f;
    for (int i = 0; i < kT; ++i) acc += wemb[idx[i] * kEmb + d] * mk[i];
    sent[bs * kEmb + d] = acc / s_cnt;
  }
}

__global__ void k_utt(const int* __restrict__ utts, const float* __restrict__ umask,
                      const float* __restrict__ sent, float* __restrict__ utt) {
  int bu = blockIdx.x;
  int b = bu / kU;
  __shared__ int idx[kUS];
  __shared__ float mk[kUS];
  __shared__ float s_cnt;
  int t = threadIdx.x;
  if (t < kUS) { idx[t] = utts[bu * kUS + t]; mk[t] = umask[bu * kUS + t]; }
  __syncthreads();
  if (t == 0) {
    float c = 0.f;
    for (int i = 0; i < kUS; ++i) c += mk[i];
    s_cnt = (c == 0.f) ? 1.f : c;
  }
  __syncthreads();
  for (int d = t; d < kEmb; d += blockDim.x) {
    float acc = 0.f;
    for (int i = 0; i < kUS; ++i) acc += sent[(b * kS + idx[i]) * kEmb + d] * mk[i];
    utt[bu * kEmb + d] = acc / s_cnt;
  }
}

__global__ void k_sess(const float* __restrict__ utt, float* __restrict__ sess) {
  int b = blockIdx.x;
  for (int d = threadIdx.x; d < kEmb; d += blockDim.x) {
    float acc = 0.f;
    for (int u = 0; u < kU; ++u) acc += utt[(b * kU + u) * kEmb + d];
    sess[b * kEmb + d] = acc * (1.f / kU);
  }
}

// gather text rows -> bf16 [kTxtRows][kEmbPad] (zero-padded K)
__global__ void k_txtgather(const int* __restrict__ aw, const float* __restrict__ wemb,
                            const float* __restrict__ sent, const float* __restrict__ utt,
                            const float* __restrict__ sess, unsigned short* __restrict__ txt) {
  int r = blockIdx.x;
  int g = r / kTxtPer, j = r - g * kTxtPer;
  const float* src;
  if (j < kW)                 src = wemb + (size_t)aw[g * kW + j] * kEmb;
  else if (j < kW + kS)       src = sent + (size_t)(g * kS + (j - kW)) * kEmb;
  else if (j < kW + kS + kU)  src = utt  + (size_t)(g * kU + (j - kW - kS)) * kEmb;
  else                        src = sess + (size_t)g * kEmb;
  for (int d = threadIdx.x; d < kEmbPad; d += blockDim.x)
    txt[(size_t)r * kEmbPad + d] = (d < kEmb) ? f2bf(src[d]) : (unsigned short)0;
}

__global__ void k_rowmap(int* __restrict__ rt, int* __restrict__ ri) {
  int i = blockIdx.x * blockDim.x + threadIdx.x;
  if (i < kTxtRows) {
    int g = i / kTxtPer, j = i - g * kTxtPer;
    int base = g * kPER;
    int node;
    if (j < kW)                 node = base + j;
    else if (j < kW + kS)       node = base + kW + kI + (j - kW);
    else if (j < kW + kS + kU)  node = base + kW + kI + kS + (j - kW - kS);
    else                        node = base + kW + kI + kS + kU;
    rt[i] = node;
  }
  if (i < kB * kI) {
    int g = i >> 6;
    ri[i] = g * kPER + kW + (i & 63);
  }
}

// fp32 -> bf16 elementwise
__global__ void k_f2bf(const float* __restrict__ in, unsigned short* __restrict__ out, int n) {
  int i = blockIdx.x * blockDim.x + threadIdx.x;
  if (i < n) out[i] = f2bf(in[i]);
}

// transpose+convert weight [K][N] fp32 -> [N][Kpad] bf16 (zero-pad k >= K)
__global__ void k_wtrans(const float* __restrict__ in, unsigned short* __restrict__ out,
                         int K, int N, int Kpad) {
  __shared__ float t[32][33];
  int tx = threadIdx.x, ty = threadIdx.y;
  int n = blockIdx.x * 32 + tx;
#pragma unroll
  for (int j = 0; j < 4; ++j) {
    int k = blockIdx.y * 32 + ty + j * 8;
    t[ty + j * 8][tx] = (k < K) ? in[(size_t)k * N + n] : 0.f;
  }
  __syncthreads();
#pragma unroll
  for (int j = 0; j < 4; ++j) {
    int nn = blockIdx.x * 32 + ty + j * 8;
    int kk = blockIdx.y * 32 + tx;
    out[(size_t)nn * Kpad + kk] = f2bf(t[tx][ty + j * 8]);
  }
}

// ---------------- bf16 MFMA GEMM ----------------
// C[M][Nc] = A[M][K](bf16) @ Bt[Nc][K](bf16)^T  (+bias), 128x128 block tile,
// 4 waves (2x2), each wave 64x64 via 4x4 grid of 16x16x32 MFMAs. BK=64.
// LDS tiles XOR-swizzled in 16B chunks: chunk c of row r stored at c^(r&7).
template <bool OBF>
__global__ __launch_bounds__(256) void k_mm(const unsigned short* __restrict__ A,
                                            const unsigned short* __restrict__ Bt,
                                            const float* __restrict__ bias,
                                            const int* __restrict__ rmap,
                                            void* __restrict__ Cout,
                                            int M, int K, int Nc) {
  __shared__ __align__(16) unsigned short As[128 * 64];
  __shared__ __align__(16) unsigned short Bs[128 * 64];
  int tid = threadIdx.x;
  int wid = tid >> 6, lane = tid & 63, quad = lane >> 4, l16 = lane & 15;
  int wm = wid >> 1, wn = wid & 1;
  int row0 = blockIdx.y * 128, col0 = blockIdx.x * 128;

  f32x4 acc[4][4];
  f32x4 zero4 = {0.f, 0.f, 0.f, 0.f};
#pragma unroll
  for (int i = 0; i < 4; ++i)
#pragma unroll
    for (int j = 0; j < 4; ++j) acc[i][j] = zero4;

  int ar = tid >> 3;        // 0..31 (row within 32-row slab)
  int ac = tid & 7;         // 16B chunk index 0..7

  for (int k0 = 0; k0 < K; k0 += 64) {
    __syncthreads();
#pragma unroll
    for (int i = 0; i < 4; ++i) {
      int r = ar + i * 32;
      int sw = ((ac ^ (r & 7)) << 3);
      // A tile
      int grow = row0 + r;
      uint4 va = make_uint4(0u, 0u, 0u, 0u);
      if (grow < M) va = *(const uint4*)(A + (size_t)grow * K + k0 + ac * 8);
      *(uint4*)&As[r * 64 + sw] = va;
      // B tile (Bt rows are output columns; Nc multiple of 128 -> no guard)
      int nrow = col0 + r;
      uint4 vb = *(const uint4*)(Bt + (size_t)nrow * K + k0 + ac * 8);
      *(uint4*)&Bs[r * 64 + sw] = vb;
    }
    __syncthreads();
#pragma unroll
    for (int s = 0; s < 2; ++s) {
      int cc = s * 4 + quad;
      bf16x8 aF[4], bF[4];
#pragma unroll
      for (int mi = 0; mi < 4; ++mi) {
        int r = wm * 64 + mi * 16 + l16;
        aF[mi] = *(const bf16x8*)&As[r * 64 + ((cc ^ (r & 7)) << 3)];
      }
#pragma unroll
      for (int ni = 0; ni < 4; ++ni) {
        int r = wn * 64 + ni * 16 + l16;
        bF[ni] = *(const bf16x8*)&Bs[r * 64 + ((cc ^ (r & 7)) << 3)];
      }
#pragma unroll
      for (int mi = 0; mi < 4; ++mi)
#pragma unroll
        for (int ni = 0; ni < 4; ++ni)
          acc[mi][ni] = __builtin_amdgcn_mfma_f32_16x16x32_bf16(aF[mi], bF[ni], acc[mi][ni], 0, 0, 0);
    }
  }

  // epilogue: C/D layout col=lane&15, row=quad*4+reg
#pragma unroll
  for (int mi = 0; mi < 4; ++mi) {
#pragma unroll
    for (int ni = 0; ni < 4; ++ni) {
      int gm0 = row0 + wm * 64 + mi * 16 + quad * 4;
      int gn  = col0 + wn * 64 + ni * 16 + l16;
      float bv = bias ? bias[gn] : 0.f;
#pragma unroll
      for (int i = 0; i < 4; ++i) {
        int r = gm0 + i;
        if (r >= M) continue;
        float v = acc[mi][ni][i] + bv;
        if (OBF) {
          int orow = rmap ? rmap[r] : r;
          ((unsigned short*)Cout)[(size_t)orow * Nc + gn] = f2bf(v);
        } else {
          ((float*)Cout)[(size_t)r * Nc + gn] = v;
        }
      }
    }
  }
}

// ---------------- per-node attention logits ----------------
__global__ void k_elr(const float* __restrict__ f, const float* __restrict__ al,
                      const float* __restrict__ ar, float* __restrict__ el,
                      float* __restrict__ er, int H, int D) {
  int v = blockIdx.x;
  int tid = threadIdx.x;
  int wave = tid >> 6, lane = tid & 63;
  for (int h = wave; h < H; h += 4) {
    float a = 0.f, b = 0.f;
    for (int d = lane; d < D; d += 64) {
      float x = f[(size_t)v * H * D + h * D + d];
      a += x * al[h * D + d];
      b += x * ar[h * D + d];
    }
    for (int off = 32; off; off >>= 1) {
      a += __shfl_down(a, off);
      b += __shfl_down(b, off);
    }
    if (lane == 0) { el[v * H + h] = a; er[v * H + h] = b; }
  }
}

// ---------------- CSR build ----------------
__global__ void k_count(const int* __restrict__ dst, int* __restrict__ cnt, int E) {
  int e = blockIdx.x * blockDim.x + threadIdx.x;
  if (e < E) atomicAdd(&cnt[dst[e]], 1);
}

__global__ void k_scan(const int* __restrict__ deg, int* __restrict__ offs, int n) {
  __shared__ int part[1024];
  int tid = threadIdx.x;
  int per = (n + 1023) >> 10;
  int start = tid * per;
  int local = 0;
  for (int i = 0; i < per; ++i) { int idx = start + i; if (idx < n) local += deg[idx]; }
  part[tid] = local;
  __syncthreads();
  for (int off = 1; off < 1024; off <<= 1) {
    int add = (tid >= off) ? part[tid - off] : 0;
    __syncthreads();
    part[tid] += add;
    __syncthreads();
  }
  int run = (tid == 0) ? 0 : part[tid - 1];
  for (int i = 0; i < per; ++i) {
    int idx = start + i;
    if (idx < n) { offs[idx] = run; run += deg[idx]; }
  }
  if (tid == 1023) offs[n] = part[1023];
}

__global__ void k_fill(const int* __restrict__ src, const int* __restrict__ dst,
                       const int* __restrict__ offs, int* __restrict__ cur,
                       int* __restrict__ csr, int E) {
  int e = blockIdx.x * blockDim.x + threadIdx.x;
  if (e < E) {
    int d = dst[e];
    int slot = offs[d] + atomicAdd(&cur[d], 1);
    csr[slot] = src[e];
  }
}

// ---------------- GAT edge-softmax + aggregate ----------------
// OBF: write bf16 (feeds next layer's GEMM A). vmap: optional dst-node remap
// (used for the final layer where only session nodes are needed).
template <int H, int D, int ACT, int OBF>
__global__ __launch_bounds__(256) void k_agg(const float* __restrict__ f,
                                             const float* __restrict__ el,
                                             const float* __restrict__ er,
                                             const int* __restrict__ offs,
                                             const int* __restrict__ csr,
                                             const float* __restrict__ bias,
                                             void* __restrict__ out,
                                             const int* __restrict__ vmap) {
  constexpr int HD = H * D;
  constexpr int K = HD / 256;
  int bv = blockIdx.x;
  int v = vmap ? vmap[bv] : bv;
  size_t orow = vmap ? (size_t)bv : (size_t)v;
  int tid = threadIdx.x;
  float erv[H];
#pragma unroll
  for (int h = 0; h < H; ++h) erv[h] = er[v * H + h];
  int e0 = offs[v], e1 = offs[v + 1];
  float m[H];
#pragma unroll
  for (int h = 0; h < H; ++h) m[h] = -1e30f;
  for (int e = e0; e < e1; ++e) {
    int s = csr[e];
#pragma unroll
    for (int h = 0; h < H; ++h) {
      float x = el[s * H + h] + erv[h];
      x = x > 0.f ? x : 0.2f * x;
      m[h] = fmaxf(m[h], x);
    }
  }
  float z[H];
  float acc[K];
#pragma unroll
  for (int h = 0; h < H; ++h) z[h] = 0.f;
#pragma unroll
  for (int k = 0; k < K; ++k) acc[k] = 0.f;
  for (int e = e0; e < e1; ++e) {
    int s = csr[e];
    float w[H];
#pragma unroll
    for (int h = 0; h < H; ++h) {
      float x = el[s * H + h] + erv[h];
      x = x > 0.f ? x : 0.2f * x;
      w[h] = expf(x - m[h]);
      z[h] += w[h];
    }
#pragma unroll
    for (int k = 0; k < K; ++k) {
      int d = (k << 8) + tid;
      int h = d / D;
      acc[k] += w[h] * f[(size_t)s * HD + d];
    }
  }
#pragma unroll
  for (int k = 0; k < K; ++k) {
    int d = (k << 8) + tid;
    int h = d / D;
    float o = acc[k] / z[h] + bias[d];
    if (ACT) o = o > 0.f ? o : expm1f(o);
    if (OBF) ((unsigned short*)out)[orow * HD + d] = f2bf(o);
    else     ((float*)out)[orow * HD + d] = o;
  }
}

// ---------------- launcher ----------------
extern "C" void kernel_launch(void* const* d_in, const int* in_sizes, int n_in,
                              void* d_out, int out_size, void* d_ws, size_t ws_size,
                              hipStream_t stream) {
  const int*   all_words   = (const int*)d_in[0];
  const float* image_feats = (const float*)d_in[1];
  const int*   sentences   = (const int*)d_in[2];
  const float* sent_mask   = (const float*)d_in[3];
  const int*   utterances  = (const int*)d_in[4];
  const float* utt_mask    = (const float*)d_in[5];
  const int*   session_ids = (const int*)d_in[6];
  const int*   edge_src    = (const int*)d_in[7];
  const int*   edge_dst    = (const int*)d_in[8];
  const float* word_embed  = (const float*)d_in[9];
  const float* text_fc_w   = (const float*)d_in[10];
  const float* text_fc_b   = (const float*)d_in[11];
  const float* image_fc_w  = (const float*)d_in[12];
  const float* image_fc_b  = (const float*)d_in[13];
  const float* gat0_fc     = (const float*)d_in[14];
  const float* gat0_al     = (const float*)d_in[15];
  const float* gat0_ar     = (const float*)d_in[16];
  const float* gat0_b      = (const float*)d_in[17];
  const float* gat1_fc     = (const float*)d_in[18];
  const float* gat1_al     = (const float*)d_in[19];
  const float* gat1_ar     = (const float*)d_in[20];
  const float* gat1_b      = (const float*)d_in[21];
  const float* gat2_fc     = (const float*)d_in[22];
  const float* gat2_al     = (const float*)d_in[23];
  const float* gat2_ar     = (const float*)d_in[24];
  const float* gat2_b      = (const float*)d_in[25];

  const int E = in_sizes[7];

  char* base = (char*)d_ws;
  size_t off = 0;
  auto alloc = [&](size_t elems, size_t esz) -> void* {
    void* p = base + off;
    off += ((elems * esz + 255) / 256) * 256;
    return p;
  };
  unsigned short* Abf  = (unsigned short*)alloc((size_t)kN * kHid, 2);       // bf16 node features
  float* fbuf          = (float*)alloc((size_t)kN * kHid, 4);                // fp32 GEMM out (f)
  unsigned short* txtbf= (unsigned short*)alloc((size_t)kTxtRows * kEmbPad, 2);
  unsigned short* imgbf= (unsigned short*)alloc((size_t)kB * kI * 2048, 2);
  unsigned short* wtTx = (unsigned short*)alloc((size_t)kHid * kEmbPad, 2);  // [1024][320]
  unsigned short* wtIm = (unsigned short*)alloc((size_t)kHid * 2048, 2);     // [1024][2048]
  unsigned short* wtG0 = (unsigned short*)alloc((size_t)kHid * kHid, 2);
  unsigned short* wtG1 = (unsigned short*)alloc((size_t)kHid * kHid, 2);
  unsigned short* wtG2 = (unsigned short*)alloc((size_t)kOut * kHid, 2);     // [512][1024]
  float* sentb  = (float*)alloc((size_t)kB * kS * kEmb, 4);
  float* uttb   = (float*)alloc((size_t)kB * kU * kEmb, 4);
  float* sessb  = (float*)alloc((size_t)kB * kEmb, 4);
  float* el     = (float*)alloc((size_t)kN * 4, 4);
  float* er     = (float*)alloc((size_t)kN * 4, 4);
  int*   offs   = (int*)alloc(kN + 1, 4);
  int*   cnt    = (int*)alloc(kN, 4);
  int*   csr    = (int*)alloc(E, 4);
  int*   rmt    = (int*)alloc(kTxtRows, 4);
  int*   rmi    = (int*)alloc(kB * kI, 4);
  (void)ws_size; (void)n_in; (void)out_size;

  // --- feature construction ---
  k_sent<<<kB * kS, 128, 0, stream>>>(sentences, sent_mask, word_embed, sentb);
  k_utt<<<kB * kU, 128, 0, stream>>>(utterances, utt_mask, sentb, uttb);
  k_sess<<<kB, 128, 0, stream>>>(uttb, sessb);
  k_txtgather<<<kTxtRows, 128, 0, stream>>>(all_words, word_embed, sentb, uttb, sessb, txtbf);
  k_rowmap<<<(kTxtRows + 255) / 256, 256, 0, stream>>>(rmt, rmi);
  k_f2bf<<<(kB * kI * 2048 + 255) / 256, 256, 0, stream>>>(image_feats, imgbf, kB * kI * 2048);

  // --- weight transpose+convert ---
  dim3 tb(32, 8);
  k_wtrans<<<dim3(kHid / 32, kEmbPad / 32), tb, 0, stream>>>(text_fc_w, wtTx, kEmb, kHid, kEmbPad);
  k_wtrans<<<dim3(kHid / 32, 2048 / 32),    tb, 0, stream>>>(image_fc_w, wtIm, 2048, kHid, 2048);
  k_wtrans<<<dim3(kHid / 32, kHid / 32),    tb, 0, stream>>>(gat0_fc, wtG0, kHid, kHid, kHid);
  k_wtrans<<<dim3(kHid / 32, kHid / 32),    tb, 0, stream>>>(gat1_fc, wtG1, kHid, kHid, kHid);
  k_wtrans<<<dim3(kOut / 32, kHid / 32),    tb, 0, stream>>>(gat2_fc, wtG2, kHid, kOut, kHid);

  // --- CSR build (overlap-able with FC) ---
  hipMemsetAsync(cnt, 0, kN * sizeof(int), stream);
  k_count<<<(E + 255) / 256, 256, 0, stream>>>(edge_dst, cnt, E);
  k_scan<<<1, 1024, 0, stream>>>(cnt, offs, kN);
  hipMemsetAsync(cnt, 0, kN * sizeof(int), stream);
  k_fill<<<(E + 255) / 256, 256, 0, stream>>>(edge_src, edge_dst, offs, cnt, csr, E);

  // --- FC projections -> bf16 node features (scattered) ---
  k_mm<true><<<dim3(kHid / 128, (kTxtRows + 127) / 128), 256, 0, stream>>>(
      txtbf, wtTx, text_fc_b, rmt, Abf, kTxtRows, kEmbPad, kHid);
  k_mm<true><<<dim3(kHid / 128, (kB * kI + 127) / 128), 256, 0, stream>>>(
      imgbf, wtIm, image_fc_b, rmi, Abf, kB * kI, 2048, kHid);

  // --- GAT layer 0 ---
  k_mm<false><<<dim3(kHid / 128, (kN + 127) / 128), 256, 0, stream>>>(
      Abf, wtG0, nullptr, nullptr, fbuf, kN, kHid, kHid);
  k_elr<<<kN, 256, 0, stream>>>(fbuf, gat0_al, gat0_ar, el, er, 4, 256);
  k_agg<4, 256, 1, 1><<<kN, 256, 0, stream>>>(fbuf, el, er, offs, csr, gat0_b, Abf, nullptr);

  // --- GAT layer 1 ---
  k_mm<false><<<dim3(kHid / 128, (kN + 127) / 128), 256, 0, stream>>>(
      Abf, wtG1, nullptr, nullptr, fbuf, kN, kHid, kHid);
  k_elr<<<kN, 256, 0, stream>>>(fbuf, gat1_al, gat1_ar, el, er, 4, 256);
  k_agg<4, 256, 1, 1><<<kN, 256, 0, stream>>>(fbuf, el, er, offs, csr, gat1_b, Abf, nullptr);

  // --- GAT layer 2 (only session nodes aggregated; output direct to d_out) ---
  k_mm<false><<<dim3(kOut / 128, (kN + 127) / 128), 256, 0, stream>>>(
      Abf, wtG2, nullptr, nullptr, fbuf, kN, kHid, kOut);
  k_elr<<<kN, 256, 0, stream>>>(fbuf, gat2_al, gat2_ar, el, er, 1, 512);
  k_agg<1, 512, 0, 0><<<kB, 256, 0, stream>>>(fbuf, el, er, offs, csr, gat2_b, (float*)d_out, session_ids);
}

// Round 3
// 586.462 us; speedup vs baseline: 3.3022x; 1.1857x over previous
//
#include <hip/hip_runtime.h>
#include <math.h>

// ---------------- problem constants ----------------
constexpr int kB = 4, kW = 2000, kI = 64, kS = 64, kT = 24, kU = 32, kUS = 2;
constexpr int kPER = kW + kI + kS + kU + 1;   // 2161 nodes per graph
constexpr int kN   = kB * kPER;               // 8644 nodes total
constexpr int kTxtPer  = kW + kS + kU + 1;    // 2097 text rows per graph
constexpr int kTxtRows = kB * kTxtPer;        // 8388 text rows
constexpr int kEmb = 300;
constexpr int kEmbPad = 320;                  // padded to multiple of 64 for MFMA K-loop
constexpr int kHid = 1024;
constexpr int kOut = 512;

typedef __attribute__((ext_vector_type(8))) short bf16x8;
typedef __attribute__((ext_vector_type(4))) float f32x4;

__device__ __forceinline__ unsigned short f2bf(float f) {
  union { float f; unsigned int u; } x; x.f = f;
  unsigned int r = x.u + 0x7FFF + ((x.u >> 16) & 1);
  return (unsigned short)(r >> 16);
}
__device__ __forceinline__ float bf2f(unsigned short u) {
  union { unsigned int u; float f; } x; x.u = ((unsigned int)u) << 16;
  return x.f;
}

// ---------------- feature construction (fp32) ----------------

__global__ void k_sent(const int* __restrict__ sents, const float* __restrict__ smask,
                       const float* __restrict__ wemb, float* __restrict__ sent) {
  int bs = blockIdx.x;
  __shared__ int idx[kT];
  __shared__ float mk[kT];
  __shared__ float s_cnt;
  int t = threadIdx.x;
  if (t < kT) { idx[t] = sents[bs * kT + t]; mk[t] = smask[bs * kT + t]; }
  __syncthreads();
  if (t == 0) {
    float c = 0.f;
    for (int i = 0; i < kT; ++i) c += mk[i];
    s_cnt = (c == 0.f) ? 1.f : c;
  }
  __syncthreads();
  for (int d = t; d < kEmb; d += blockDim.x) {
    float acc = 0.f;
    for (int i = 0; i < kT; ++i) acc += wemb[idx[i] * kEmb + d] * mk[i];
    sent[bs * kEmb + d] = acc / s_cnt;
  }
}

__global__ void k_utt(const int* __restrict__ utts, const float* __restrict__ umask,
                      const float* __restrict__ sent, float* __restrict__ utt) {
  int bu = blockIdx.x;
  int b = bu / kU;
  __shared__ int idx[kUS];
  __shared__ float mk[kUS];
  __shared__ float s_cnt;
  int t = threadIdx.x;
  if (t < kUS) { idx[t] = utts[bu * kUS + t]; mk[t] = umask[bu * kUS + t]; }
  __syncthreads();
  if (t == 0) {
    float c = 0.f;
    for (int i = 0; i < kUS; ++i) c += mk[i];
    s_cnt = (c == 0.f) ? 1.f : c;
  }
  __syncthreads();
  for (int d = t; d < kEmb; d += blockDim.x) {
    float acc = 0.f;
    for (int i = 0; i < kUS; ++i) acc += sent[(b * kS + idx[i]) * kEmb + d] * mk[i];
    utt[bu * kEmb + d] = acc / s_cnt;
  }
}

__global__ void k_sess(const float* __restrict__ utt, float* __restrict__ sess) {
  int b = blockIdx.x;
  for (int d = threadIdx.x; d < kEmb; d += blockDim.x) {
    float acc = 0.f;
    for (int u = 0; u < kU; ++u) acc += utt[(b * kU + u) * kEmb + d];
    sess[b * kEmb + d] = acc * (1.f / kU);
  }
}

// gather text rows -> bf16 [kTxtRows][kEmbPad] (zero-padded K)
__global__ void k_txtgather(const int* __restrict__ aw, const float* __restrict__ wemb,
                            const float* __restrict__ sent, const float* __restrict__ utt,
                            const float* __restrict__ sess, unsigned short* __restrict__ txt) {
  int r = blockIdx.x;
  int g = r / kTxtPer, j = r - g * kTxtPer;
  const float* src;
  if (j < kW)                 src = wemb + (size_t)aw[g * kW + j] * kEmb;
  else if (j < kW + kS)       src = sent + (size_t)(g * kS + (j - kW)) * kEmb;
  else if (j < kW + kS + kU)  src = utt  + (size_t)(g * kU + (j - kW - kS)) * kEmb;
  else                        src = sess + (size_t)g * kEmb;
  for (int d = threadIdx.x; d < kEmbPad; d += blockDim.x)
    txt[(size_t)r * kEmbPad + d] = (d < kEmb) ? f2bf(src[d]) : (unsigned short)0;
}

__global__ void k_rowmap(int* __restrict__ rt, int* __restrict__ ri) {
  int i = blockIdx.x * blockDim.x + threadIdx.x;
  if (i < kTxtRows) {
    int g = i / kTxtPer, j = i - g * kTxtPer;
    int base = g * kPER;
    int node;
    if (j < kW)                 node = base + j;
    else if (j < kW + kS)       node = base + kW + kI + (j - kW);
    else if (j < kW + kS + kU)  node = base + kW + kI + kS + (j - kW - kS);
    else                        node = base + kW + kI + kS + kU;
    rt[i] = node;
  }
  if (i < kB * kI) {
    int g = i >> 6;
    ri[i] = g * kPER + kW + (i & 63);
  }
}

// fp32 -> bf16 elementwise
__global__ void k_f2bf(const float* __restrict__ in, unsigned short* __restrict__ out, int n) {
  int i = blockIdx.x * blockDim.x + threadIdx.x;
  if (i < n) out[i] = f2bf(in[i]);
}

// transpose+convert weight [K][N] fp32 -> [N][Kpad] bf16 (zero-pad k >= K)
__global__ void k_wtrans(const float* __restrict__ in, unsigned short* __restrict__ out,
                         int K, int N, int Kpad) {
  __shared__ float t[32][33];
  int tx = threadIdx.x, ty = threadIdx.y;
  int n = blockIdx.x * 32 + tx;
#pragma unroll
  for (int j = 0; j < 4; ++j) {
    int k = blockIdx.y * 32 + ty + j * 8;
    t[ty + j * 8][tx] = (k < K) ? in[(size_t)k * N + n] : 0.f;
  }
  __syncthreads();
#pragma unroll
  for (int j = 0; j < 4; ++j) {
    int nn = blockIdx.x * 32 + ty + j * 8;
    int kk = blockIdx.y * 32 + tx;
    out[(size_t)nn * Kpad + kk] = f2bf(t[tx][ty + j * 8]);
  }
}

// ---------------- bf16 MFMA GEMM ----------------
// C[M][Nc] = A[M][K](bf16) @ Bt[Nc][K](bf16)^T  (+bias), 128x128 block tile,
// 4 waves (2x2), each wave 64x64 via 4x4 grid of 16x16x32 MFMAs. BK=64.
// LDS tiles XOR-swizzled in 16B chunks: chunk c of row r stored at c^(r&7).
template <bool OBF>
__global__ __launch_bounds__(256) void k_mm(const unsigned short* __restrict__ A,
                                            const unsigned short* __restrict__ Bt,
                                            const float* __restrict__ bias,
                                            const int* __restrict__ rmap,
                                            void* __restrict__ Cout,
                                            int M, int K, int Nc) {
  __shared__ __align__(16) unsigned short As[128 * 64];
  __shared__ __align__(16) unsigned short Bs[128 * 64];
  int tid = threadIdx.x;
  int wid = tid >> 6, lane = tid & 63, quad = lane >> 4, l16 = lane & 15;
  int wm = wid >> 1, wn = wid & 1;
  int row0 = blockIdx.y * 128, col0 = blockIdx.x * 128;

  f32x4 acc[4][4];
  f32x4 zero4 = {0.f, 0.f, 0.f, 0.f};
#pragma unroll
  for (int i = 0; i < 4; ++i)
#pragma unroll
    for (int j = 0; j < 4; ++j) acc[i][j] = zero4;

  int ar = tid >> 3;        // 0..31 (row within 32-row slab)
  int ac = tid & 7;         // 16B chunk index 0..7

  for (int k0 = 0; k0 < K; k0 += 64) {
    __syncthreads();
#pragma unroll
    for (int i = 0; i < 4; ++i) {
      int r = ar + i * 32;
      int sw = ((ac ^ (r & 7)) << 3);
      int grow = row0 + r;
      uint4 va = make_uint4(0u, 0u, 0u, 0u);
      if (grow < M) va = *(const uint4*)(A + (size_t)grow * K + k0 + ac * 8);
      *(uint4*)&As[r * 64 + sw] = va;
      int nrow = col0 + r;
      uint4 vb = *(const uint4*)(Bt + (size_t)nrow * K + k0 + ac * 8);
      *(uint4*)&Bs[r * 64 + sw] = vb;
    }
    __syncthreads();
#pragma unroll
    for (int s = 0; s < 2; ++s) {
      int cc = s * 4 + quad;
      bf16x8 aF[4], bF[4];
#pragma unroll
      for (int mi = 0; mi < 4; ++mi) {
        int r = wm * 64 + mi * 16 + l16;
        aF[mi] = *(const bf16x8*)&As[r * 64 + ((cc ^ (r & 7)) << 3)];
      }
#pragma unroll
      for (int ni = 0; ni < 4; ++ni) {
        int r = wn * 64 + ni * 16 + l16;
        bF[ni] = *(const bf16x8*)&Bs[r * 64 + ((cc ^ (r & 7)) << 3)];
      }
#pragma unroll
      for (int mi = 0; mi < 4; ++mi)
#pragma unroll
        for (int ni = 0; ni < 4; ++ni)
          acc[mi][ni] = __builtin_amdgcn_mfma_f32_16x16x32_bf16(aF[mi], bF[ni], acc[mi][ni], 0, 0, 0);
    }
  }

  // epilogue: C/D layout col=lane&15, row=quad*4+reg
#pragma unroll
  for (int mi = 0; mi < 4; ++mi) {
#pragma unroll
    for (int ni = 0; ni < 4; ++ni) {
      int gm0 = row0 + wm * 64 + mi * 16 + quad * 4;
      int gn  = col0 + wn * 64 + ni * 16 + l16;
      float bv = bias ? bias[gn] : 0.f;
#pragma unroll
      for (int i = 0; i < 4; ++i) {
        int r = gm0 + i;
        if (r >= M) continue;
        float v = acc[mi][ni][i] + bv;
        if (OBF) {
          int orow = rmap ? rmap[r] : r;
          ((unsigned short*)Cout)[(size_t)orow * Nc + gn] = f2bf(v);
        } else {
          ((float*)Cout)[(size_t)r * Nc + gn] = v;
        }
      }
    }
  }
}

// ---------------- attention logits, bf16 f, H=4 D=256 ----------------
__global__ void k_elr4(const unsigned short* __restrict__ f, const float* __restrict__ al,
                       const float* __restrict__ ar, float* __restrict__ el,
                       float* __restrict__ er) {
  int v = blockIdx.x;
  int h = threadIdx.x >> 6, lane = threadIdx.x & 63;
  int d = lane * 4;
  ushort4 fv = *(const ushort4*)(f + (size_t)v * 1024 + h * 256 + d);
  float4 av = *(const float4*)(al + h * 256 + d);
  float4 rv = *(const float4*)(ar + h * 256 + d);
  float x0 = bf2f(fv.x), x1 = bf2f(fv.y), x2 = bf2f(fv.z), x3 = bf2f(fv.w);
  float a = x0 * av.x + x1 * av.y + x2 * av.z + x3 * av.w;
  float b = x0 * rv.x + x1 * rv.y + x2 * rv.z + x3 * rv.w;
#pragma unroll
  for (int off = 32; off; off >>= 1) {
    a += __shfl_down(a, off);
    b += __shfl_down(b, off);
  }
  if (lane == 0) { el[v * 4 + h] = a; er[v * 4 + h] = b; }
}

// generic fp32 logits (layer 2)
__global__ void k_elr(const float* __restrict__ f, const float* __restrict__ al,
                      const float* __restrict__ ar, float* __restrict__ el,
                      float* __restrict__ er, int H, int D) {
  int v = blockIdx.x;
  int tid = threadIdx.x;
  int wave = tid >> 6, lane = tid & 63;
  for (int h = wave; h < H; h += 4) {
    float a = 0.f, b = 0.f;
    for (int d = lane; d < D; d += 64) {
      float x = f[(size_t)v * H * D + h * D + d];
      a += x * al[h * D + d];
      b += x * ar[h * D + d];
    }
    for (int off = 32; off; off >>= 1) {
      a += __shfl_down(a, off);
      b += __shfl_down(b, off);
    }
    if (lane == 0) { el[v * H + h] = a; er[v * H + h] = b; }
  }
}

// ---------------- CSR build ----------------
__global__ void k_count(const int* __restrict__ dst, int* __restrict__ cnt, int E) {
  int e = blockIdx.x * blockDim.x + threadIdx.x;
  if (e < E) atomicAdd(&cnt[dst[e]], 1);
}

__global__ void k_scan(const int* __restrict__ deg, int* __restrict__ offs, int n) {
  __shared__ int part[1024];
  int tid = threadIdx.x;
  int per = (n + 1023) >> 10;
  int start = tid * per;
  int local = 0;
  for (int i = 0; i < per; ++i) { int idx = start + i; if (idx < n) local += deg[idx]; }
  part[tid] = local;
  __syncthreads();
  for (int off = 1; off < 1024; off <<= 1) {
    int add = (tid >= off) ? part[tid - off] : 0;
    __syncthreads();
    part[tid] += add;
    __syncthreads();
  }
  int run = (tid == 0) ? 0 : part[tid - 1];
  for (int i = 0; i < per; ++i) {
    int idx = start + i;
    if (idx < n) { offs[idx] = run; run += deg[idx]; }
  }
  if (tid == 1023) offs[n] = part[1023];
}

__global__ void k_fill(const int* __restrict__ src, const int* __restrict__ dst,
                       const int* __restrict__ offs, int* __restrict__ cur,
                       int* __restrict__ csr, int E) {
  int e = blockIdx.x * blockDim.x + threadIdx.x;
  if (e < E) {
    int d = dst[e];
    int slot = offs[d] + atomicAdd(&cur[d], 1);
    csr[slot] = src[e];
  }
}

// ---------------- per-edge softmax weights (H=4), one thread per (dst,head) ----------------
__global__ void k_alpha(const float* __restrict__ el, const float* __restrict__ er,
                        const int* __restrict__ offs, const int* __restrict__ csr,
                        float* __restrict__ alpha, float* __restrict__ zr) {
  int i = blockIdx.x * blockDim.x + threadIdx.x;
  if (i >= kN * 4) return;
  int v = i >> 2, h = i & 3;
  float erv = er[i];
  int e0 = offs[v], e1 = offs[v + 1];
  float m = -1e30f;
  for (int e = e0; e < e1; ++e) {
    float x = el[csr[e] * 4 + h] + erv;
    x = x > 0.f ? x : 0.2f * x;
    m = fmaxf(m, x);
  }
  float z = 0.f;
  for (int e = e0; e < e1; ++e) {
    float x = el[csr[e] * 4 + h] + erv;
    x = x > 0.f ? x : 0.2f * x;
    float w = expf(x - m);
    z += w;
    alpha[e * 4 + h] = w;
  }
  zr[i] = 1.f / z;
}

// ---------------- aggregation: bf16 gather with precomputed alpha (H=4, D=256, ELU) ----------------
__global__ __launch_bounds__(256) void k_agg2(const unsigned short* __restrict__ f,
                                              const float* __restrict__ alpha,
                                              const float* __restrict__ zr,
                                              const int* __restrict__ offs,
                                              const int* __restrict__ csr,
                                              const float* __restrict__ bias,
                                              unsigned short* __restrict__ out) {
  int v = blockIdx.x;
  int tid = threadIdx.x;
  int h = tid >> 6;            // 4 elems per thread, all in head h
  int d0 = tid * 4;
  int e0 = offs[v], e1 = offs[v + 1];
  float a0 = 0.f, a1 = 0.f, a2 = 0.f, a3 = 0.f;
  for (int e = e0; e < e1; ++e) {
    int s = csr[e];
    float w = alpha[e * 4 + h];
    ushort4 fv = *(const ushort4*)(f + (size_t)s * 1024 + d0);
    a0 += w * bf2f(fv.x);
    a1 += w * bf2f(fv.y);
    a2 += w * bf2f(fv.z);
    a3 += w * bf2f(fv.w);
  }
  float rz = zr[v * 4 + h];
  float4 bv = *(const float4*)(bias + d0);
  float o0 = a0 * rz + bv.x, o1 = a1 * rz + bv.y, o2 = a2 * rz + bv.z, o3 = a3 * rz + bv.w;
  o0 = o0 > 0.f ? o0 : expm1f(o0);
  o1 = o1 > 0.f ? o1 : expm1f(o1);
  o2 = o2 > 0.f ? o2 : expm1f(o2);
  o3 = o3 > 0.f ? o3 : expm1f(o3);
  ushort4 ov;
  ov.x = f2bf(o0); ov.y = f2bf(o1); ov.z = f2bf(o2); ov.w = f2bf(o3);
  *(ushort4*)(out + (size_t)v * 1024 + d0) = ov;
}

// ---------------- layer-2 aggregation (fp32 f, H=1 D=512, only session nodes) ----------------
__global__ __launch_bounds__(256) void k_agg_final(const float* __restrict__ f,
                                                   const float* __restrict__ el,
                                                   const float* __restrict__ er,
                                                   const int* __restrict__ offs,
                                                   const int* __restrict__ csr,
                                                   const float* __restrict__ bias,
                                                   float* __restrict__ out,
                                                   const int* __restrict__ vmap) {
  constexpr int HD = 512;
  int bv = blockIdx.x;
  int v = vmap[bv];
  int tid = threadIdx.x;
  float erv = er[v];
  int e0 = offs[v], e1 = offs[v + 1];
  float m = -1e30f;
  for (int e = e0; e < e1; ++e) {
    float x = el[csr[e]] + erv;
    x = x > 0.f ? x : 0.2f * x;
    m = fmaxf(m, x);
  }
  float z = 0.f;
  float acc0 = 0.f, acc1 = 0.f;
  for (int e = e0; e < e1; ++e) {
    int s = csr[e];
    float x = el[s] + erv;
    x = x > 0.f ? x : 0.2f * x;
    float w = expf(x - m);
    z += w;
    acc0 += w * f[(size_t)s * HD + tid];
    acc1 += w * f[(size_t)s * HD + 256 + tid];
  }
  out[(size_t)bv * HD + tid] = acc0 / z + bias[tid];
  out[(size_t)bv * HD + 256 + tid] = acc1 / z + bias[256 + tid];
}

// ---------------- launcher ----------------
extern "C" void kernel_launch(void* const* d_in, const int* in_sizes, int n_in,
                              void* d_out, int out_size, void* d_ws, size_t ws_size,
                              hipStream_t stream) {
  const int*   all_words   = (const int*)d_in[0];
  const float* image_feats = (const float*)d_in[1];
  const int*   sentences   = (const int*)d_in[2];
  const float* sent_mask   = (const float*)d_in[3];
  const int*   utterances  = (const int*)d_in[4];
  const float* utt_mask    = (const float*)d_in[5];
  const int*   session_ids = (const int*)d_in[6];
  const int*   edge_src    = (const int*)d_in[7];
  const int*   edge_dst    = (const int*)d_in[8];
  const float* word_embed  = (const float*)d_in[9];
  const float* text_fc_w   = (const float*)d_in[10];
  const float* text_fc_b   = (const float*)d_in[11];
  const float* image_fc_w  = (const float*)d_in[12];
  const float* image_fc_b  = (const float*)d_in[13];
  const float* gat0_fc     = (const float*)d_in[14];
  const float* gat0_al     = (const float*)d_in[15];
  const float* gat0_ar     = (const float*)d_in[16];
  const float* gat0_b      = (const float*)d_in[17];
  const float* gat1_fc     = (const float*)d_in[18];
  const float* gat1_al     = (const float*)d_in[19];
  const float* gat1_ar     = (const float*)d_in[20];
  const float* gat1_b      = (const float*)d_in[21];
  const float* gat2_fc     = (const float*)d_in[22];
  const float* gat2_al     = (const float*)d_in[23];
  const float* gat2_ar     = (const float*)d_in[24];
  const float* gat2_b      = (const float*)d_in[25];

  const int E = in_sizes[7];

  char* base = (char*)d_ws;
  size_t off = 0;
  auto alloc = [&](size_t elems, size_t esz) -> void* {
    void* p = base + off;
    off += ((elems * esz + 255) / 256) * 256;
    return p;
  };
  unsigned short* Abf   = (unsigned short*)alloc((size_t)kN * kHid, 2);      // bf16 node features
  unsigned short* fbf   = (unsigned short*)alloc((size_t)kN * kHid, 2);      // bf16 f (layers 0/1)
  float*          f32b  = (float*)alloc((size_t)kN * kOut, 4);               // fp32 f (layer 2)
  unsigned short* txtbf = (unsigned short*)alloc((size_t)kTxtRows * kEmbPad, 2);
  unsigned short* imgbf = (unsigned short*)alloc((size_t)kB * kI * 2048, 2);
  unsigned short* wtTx  = (unsigned short*)alloc((size_t)kHid * kEmbPad, 2);
  unsigned short* wtIm  = (unsigned short*)alloc((size_t)kHid * 2048, 2);
  unsigned short* wtG0  = (unsigned short*)alloc((size_t)kHid * kHid, 2);
  unsigned short* wtG1  = (unsigned short*)alloc((size_t)kHid * kHid, 2);
  unsigned short* wtG2  = (unsigned short*)alloc((size_t)kOut * kHid, 2);
  float* sentb  = (float*)alloc((size_t)kB * kS * kEmb, 4);
  float* uttb   = (float*)alloc((size_t)kB * kU * kEmb, 4);
  float* sessb  = (float*)alloc((size_t)kB * kEmb, 4);
  float* el     = (float*)alloc((size_t)kN * 4, 4);
  float* er     = (float*)alloc((size_t)kN * 4, 4);
  float* alphab = (float*)alloc((size_t)E * 4, 4);
  float* zrb    = (float*)alloc((size_t)kN * 4, 4);
  int*   offs   = (int*)alloc(kN + 1, 4);
  int*   cnt    = (int*)alloc(kN, 4);
  int*   csr    = (int*)alloc(E, 4);
  int*   rmt    = (int*)alloc(kTxtRows, 4);
  int*   rmi    = (int*)alloc(kB * kI, 4);
  (void)ws_size; (void)n_in; (void)out_size;

  // --- feature construction ---
  k_sent<<<kB * kS, 128, 0, stream>>>(sentences, sent_mask, word_embed, sentb);
  k_utt<<<kB * kU, 128, 0, stream>>>(utterances, utt_mask, sentb, uttb);
  k_sess<<<kB, 128, 0, stream>>>(uttb, sessb);
  k_txtgather<<<kTxtRows, 128, 0, stream>>>(all_words, word_embed, sentb, uttb, sessb, txtbf);
  k_rowmap<<<(kTxtRows + 255) / 256, 256, 0, stream>>>(rmt, rmi);
  k_f2bf<<<(kB * kI * 2048 + 255) / 256, 256, 0, stream>>>(image_feats, imgbf, kB * kI * 2048);

  // --- weight transpose+convert ---
  dim3 tb(32, 8);
  k_wtrans<<<dim3(kHid / 32, kEmbPad / 32), tb, 0, stream>>>(text_fc_w, wtTx, kEmb, kHid, kEmbPad);
  k_wtrans<<<dim3(kHid / 32, 2048 / 32),    tb, 0, stream>>>(image_fc_w, wtIm, 2048, kHid, 2048);
  k_wtrans<<<dim3(kHid / 32, kHid / 32),    tb, 0, stream>>>(gat0_fc, wtG0, kHid, kHid, kHid);
  k_wtrans<<<dim3(kHid / 32, kHid / 32),    tb, 0, stream>>>(gat1_fc, wtG1, kHid, kHid, kHid);
  k_wtrans<<<dim3(kOut / 32, kHid / 32),    tb, 0, stream>>>(gat2_fc, wtG2, kHid, kOut, kHid);

  // --- CSR build ---
  hipMemsetAsync(cnt, 0, kN * sizeof(int), stream);
  k_count<<<(E + 255) / 256, 256, 0, stream>>>(edge_dst, cnt, E);
  k_scan<<<1, 1024, 0, stream>>>(cnt, offs, kN);
  hipMemsetAsync(cnt, 0, kN * sizeof(int), stream);
  k_fill<<<(E + 255) / 256, 256, 0, stream>>>(edge_src, edge_dst, offs, cnt, csr, E);

  // --- FC projections -> bf16 node features (scattered) ---
  k_mm<true><<<dim3(kHid / 128, (kTxtRows + 127) / 128), 256, 0, stream>>>(
      txtbf, wtTx, text_fc_b, rmt, Abf, kTxtRows, kEmbPad, kHid);
  k_mm<true><<<dim3(kHid / 128, (kB * kI + 127) / 128), 256, 0, stream>>>(
      imgbf, wtIm, image_fc_b, rmi, Abf, kB * kI, 2048, kHid);

  // --- GAT layer 0 ---
  k_mm<true><<<dim3(kHid / 128, (kN + 127) / 128), 256, 0, stream>>>(
      Abf, wtG0, nullptr, nullptr, fbf, kN, kHid, kHid);
  k_elr4<<<kN, 256, 0, stream>>>(fbf, gat0_al, gat0_ar, el, er);
  k_alpha<<<(kN * 4 + 255) / 256, 256, 0, stream>>>(el, er, offs, csr, alphab, zrb);
  k_agg2<<<kN, 256, 0, stream>>>(fbf, alphab, zrb, offs, csr, gat0_b, Abf);

  // --- GAT layer 1 ---
  k_mm<true><<<dim3(kHid / 128, (kN + 127) / 128), 256, 0, stream>>>(
      Abf, wtG1, nullptr, nullptr, fbf, kN, kHid, kHid);
  k_elr4<<<kN, 256, 0, stream>>>(fbf, gat1_al, gat1_ar, el, er);
  k_alpha<<<(kN * 4 + 255) / 256, 256, 0, stream>>>(el, er, offs, csr, alphab, zrb);
  k_agg2<<<kN, 256, 0, stream>>>(fbf, alphab, zrb, offs, csr, gat1_b, Abf);

  // --- GAT layer 2 (only session nodes aggregated; output direct to d_out) ---
  k_mm<false><<<dim3(kOut / 128, (kN + 127) / 128), 256, 0, stream>>>(
      Abf, wtG2, nullptr, nullptr, f32b, kN, kHid, kOut);
  k_elr<<<kN, 256, 0, stream>>>(f32b, gat2_al, gat2_ar, el, er, 1, 512);
  k_agg_final<<<kB, 256, 0, stream>>>(f32b, el, er, offs, csr, gat2_b, (float*)d_out, session_ids);
}

// Round 4
// 501.743 us; speedup vs baseline: 3.8597x; 1.1688x over previous
//
#include <hip/hip_runtime.h>
#include <math.h>

// ---------------- problem constants ----------------
constexpr int kB = 4, kW = 2000, kI = 64, kS = 64, kT = 24, kU = 32, kUS = 2;
constexpr int kPER = kW + kI + kS + kU + 1;   // 2161 nodes per graph
constexpr int kN   = kB * kPER;               // 8644 nodes total
constexpr int kTxtPer  = kW + kS + kU + 1;    // 2097 text rows per graph
constexpr int kTxtRows = kB * kTxtPer;        // 8388 text rows
constexpr int kEmb = 300;
constexpr int kEmbPad = 320;                  // padded to multiple of 64 for MFMA K-loop
constexpr int kHid = 1024;
constexpr int kOut = 512;
constexpr int kCap = 256;                     // max gathered rows for sparse gat2

typedef __attribute__((ext_vector_type(8))) short bf16x8;
typedef __attribute__((ext_vector_type(4))) float f32x4;

__device__ __forceinline__ unsigned short f2bf(float f) {
  union { float f; unsigned int u; } x; x.f = f;
  unsigned int r = x.u + 0x7FFF + ((x.u >> 16) & 1);
  return (unsigned short)(r >> 16);
}
__device__ __forceinline__ float bf2f(unsigned short u) {
  union { unsigned int u; float f; } x; x.u = ((unsigned int)u) << 16;
  return x.f;
}

// ---------------- feature construction (fp32) ----------------

__global__ void k_sent(const int* __restrict__ sents, const float* __restrict__ smask,
                       const float* __restrict__ wemb, float* __restrict__ sent) {
  int bs = blockIdx.x;
  __shared__ int idx[kT];
  __shared__ float mk[kT];
  __shared__ float s_cnt;
  int t = threadIdx.x;
  if (t < kT) { idx[t] = sents[bs * kT + t]; mk[t] = smask[bs * kT + t]; }
  __syncthreads();
  if (t == 0) {
    float c = 0.f;
    for (int i = 0; i < kT; ++i) c += mk[i];
    s_cnt = (c == 0.f) ? 1.f : c;
  }
  __syncthreads();
  for (int d = t; d < kEmb; d += blockDim.x) {
    float acc = 0.f;
    for (int i = 0; i < kT; ++i) acc += wemb[idx[i] * kEmb + d] * mk[i];
    sent[bs * kEmb + d] = acc / s_cnt;
  }
}

__global__ void k_utt(const int* __restrict__ utts, const float* __restrict__ umask,
                      const float* __restrict__ sent, float* __restrict__ utt) {
  int bu = blockIdx.x;
  int b = bu / kU;
  __shared__ int idx[kUS];
  __shared__ float mk[kUS];
  __shared__ float s_cnt;
  int t = threadIdx.x;
  if (t < kUS) { idx[t] = utts[bu * kUS + t]; mk[t] = umask[bu * kUS + t]; }
  __syncthreads();
  if (t == 0) {
    float c = 0.f;
    for (int i = 0; i < kUS; ++i) c += mk[i];
    s_cnt = (c == 0.f) ? 1.f : c;
  }
  __syncthreads();
  for (int d = t; d < kEmb; d += blockDim.x) {
    float acc = 0.f;
    for (int i = 0; i < kUS; ++i) acc += sent[(b * kS + idx[i]) * kEmb + d] * mk[i];
    utt[bu * kEmb + d] = acc / s_cnt;
  }
}

__global__ void k_sess(const float* __restrict__ utt, float* __restrict__ sess) {
  int b = blockIdx.x;
  for (int d = threadIdx.x; d < kEmb; d += blockDim.x) {
    float acc = 0.f;
    for (int u = 0; u < kU; ++u) acc += utt[(b * kU + u) * kEmb + d];
    sess[b * kEmb + d] = acc * (1.f / kU);
  }
}

// gather text rows -> bf16 [kTxtRows][kEmbPad] (zero-padded K)
__global__ void k_txtgather(const int* __restrict__ aw, const float* __restrict__ wemb,
                            const float* __restrict__ sent, const float* __restrict__ utt,
                            const float* __restrict__ sess, unsigned short* __restrict__ txt) {
  int r = blockIdx.x;
  int g = r / kTxtPer, j = r - g * kTxtPer;
  const float* src;
  if (j < kW)                 src = wemb + (size_t)aw[g * kW + j] * kEmb;
  else if (j < kW + kS)       src = sent + (size_t)(g * kS + (j - kW)) * kEmb;
  else if (j < kW + kS + kU)  src = utt  + (size_t)(g * kU + (j - kW - kS)) * kEmb;
  else                        src = sess + (size_t)g * kEmb;
  for (int d = threadIdx.x; d < kEmbPad; d += blockDim.x)
    txt[(size_t)r * kEmbPad + d] = (d < kEmb) ? f2bf(src[d]) : (unsigned short)0;
}

__global__ void k_rowmap(int* __restrict__ rt, int* __restrict__ ri) {
  int i = blockIdx.x * blockDim.x + threadIdx.x;
  if (i < kTxtRows) {
    int g = i / kTxtPer, j = i - g * kTxtPer;
    int base = g * kPER;
    int node;
    if (j < kW)                 node = base + j;
    else if (j < kW + kS)       node = base + kW + kI + (j - kW);
    else if (j < kW + kS + kU)  node = base + kW + kI + kS + (j - kW - kS);
    else                        node = base + kW + kI + kS + kU;
    rt[i] = node;
  }
  if (i < kB * kI) {
    int g = i >> 6;
    ri[i] = g * kPER + kW + (i & 63);
  }
}

// fp32 -> bf16 elementwise
__global__ void k_f2bf(const float* __restrict__ in, unsigned short* __restrict__ out, int n) {
  int i = blockIdx.x * blockDim.x + threadIdx.x;
  if (i < n) out[i] = f2bf(in[i]);
}

// transpose+convert weight [K][N] fp32 -> [N][Kpad] bf16 (zero-pad k >= K)
__global__ void k_wtrans(const float* __restrict__ in, unsigned short* __restrict__ out,
                         int K, int N, int Kpad) {
  __shared__ float t[32][33];
  int tx = threadIdx.x, ty = threadIdx.y;
  int n = blockIdx.x * 32 + tx;
#pragma unroll
  for (int j = 0; j < 4; ++j) {
    int k = blockIdx.y * 32 + ty + j * 8;
    t[ty + j * 8][tx] = (k < K) ? in[(size_t)k * N + n] : 0.f;
  }
  __syncthreads();
#pragma unroll
  for (int j = 0; j < 4; ++j) {
    int nn = blockIdx.x * 32 + ty + j * 8;
    int kk = blockIdx.y * 32 + tx;
    out[(size_t)nn * Kpad + kk] = f2bf(t[tx][ty + j * 8]);
  }
}

// ---------------- bf16 MFMA GEMM (128x128 tile) ----------------
template <bool OBF>
__global__ __launch_bounds__(256) void k_mm(const unsigned short* __restrict__ A,
                                            const unsigned short* __restrict__ Bt,
                                            const float* __restrict__ bias,
                                            const int* __restrict__ rmap,
                                            void* __restrict__ Cout,
                                            int M, int K, int Nc) {
  __shared__ __align__(16) unsigned short As[128 * 64];
  __shared__ __align__(16) unsigned short Bs[128 * 64];
  int tid = threadIdx.x;
  int wid = tid >> 6, lane = tid & 63, quad = lane >> 4, l16 = lane & 15;
  int wm = wid >> 1, wn = wid & 1;
  int row0 = blockIdx.y * 128, col0 = blockIdx.x * 128;

  f32x4 acc[4][4];
  f32x4 zero4 = {0.f, 0.f, 0.f, 0.f};
#pragma unroll
  for (int i = 0; i < 4; ++i)
#pragma unroll
    for (int j = 0; j < 4; ++j) acc[i][j] = zero4;

  int ar = tid >> 3;        // 0..31
  int ac = tid & 7;         // 16B chunk 0..7

  for (int k0 = 0; k0 < K; k0 += 64) {
    __syncthreads();
#pragma unroll
    for (int i = 0; i < 4; ++i) {
      int r = ar + i * 32;
      int sw = ((ac ^ (r & 7)) << 3);
      int grow = row0 + r;
      uint4 va = make_uint4(0u, 0u, 0u, 0u);
      if (grow < M) va = *(const uint4*)(A + (size_t)grow * K + k0 + ac * 8);
      *(uint4*)&As[r * 64 + sw] = va;
      int nrow = col0 + r;
      uint4 vb = *(const uint4*)(Bt + (size_t)nrow * K + k0 + ac * 8);
      *(uint4*)&Bs[r * 64 + sw] = vb;
    }
    __syncthreads();
#pragma unroll
    for (int s = 0; s < 2; ++s) {
      int cc = s * 4 + quad;
      bf16x8 aF[4], bF[4];
#pragma unroll
      for (int mi = 0; mi < 4; ++mi) {
        int r = wm * 64 + mi * 16 + l16;
        aF[mi] = *(const bf16x8*)&As[r * 64 + ((cc ^ (r & 7)) << 3)];
      }
#pragma unroll
      for (int ni = 0; ni < 4; ++ni) {
        int r = wn * 64 + ni * 16 + l16;
        bF[ni] = *(const bf16x8*)&Bs[r * 64 + ((cc ^ (r & 7)) << 3)];
      }
#pragma unroll
      for (int mi = 0; mi < 4; ++mi)
#pragma unroll
        for (int ni = 0; ni < 4; ++ni)
          acc[mi][ni] = __builtin_amdgcn_mfma_f32_16x16x32_bf16(aF[mi], bF[ni], acc[mi][ni], 0, 0, 0);
    }
  }

#pragma unroll
  for (int mi = 0; mi < 4; ++mi) {
#pragma unroll
    for (int ni = 0; ni < 4; ++ni) {
      int gm0 = row0 + wm * 64 + mi * 16 + quad * 4;
      int gn  = col0 + wn * 64 + ni * 16 + l16;
      float bv = bias ? bias[gn] : 0.f;
#pragma unroll
      for (int i = 0; i < 4; ++i) {
        int r = gm0 + i;
        if (r >= M) continue;
        float v = acc[mi][ni][i] + bv;
        if (OBF) {
          int orow = rmap ? rmap[r] : r;
          ((unsigned short*)Cout)[(size_t)orow * Nc + gn] = f2bf(v);
        } else {
          ((float*)Cout)[(size_t)r * Nc + gn] = v;
        }
      }
    }
  }
}

// ---------------- split-K bf16 MFMA GEMM (64x64 tile, optional A-row gather) ----------------
// C[M][Nc] (fp32, pre-zeroed) += A[rowlist[m]][k0:k1] @ Bt[n][k0:k1]^T via atomicAdd.
__global__ __launch_bounds__(256) void k_mm_sk(const unsigned short* __restrict__ A,
                                               const unsigned short* __restrict__ Bt,
                                               const int* __restrict__ rowlist,
                                               float* __restrict__ C,
                                               int M, int K, int Nc, int Kc) {
  __shared__ __align__(16) unsigned short As[64 * 64];
  __shared__ __align__(16) unsigned short Bs[64 * 64];
  int tid = threadIdx.x;
  int wid = tid >> 6, lane = tid & 63, quad = lane >> 4, l16 = lane & 15;
  int row0 = blockIdx.y * 64, col0 = blockIdx.x * 64;
  int k0 = blockIdx.z * Kc;
  int k1 = k0 + Kc; if (k1 > K) k1 = K;

  f32x4 acc[4];
  f32x4 zero4 = {0.f, 0.f, 0.f, 0.f};
#pragma unroll
  for (int i = 0; i < 4; ++i) acc[i] = zero4;

  int ar = tid >> 3;   // 0..31
  int ac = tid & 7;

  for (int kk = k0; kk < k1; kk += 64) {
    __syncthreads();
#pragma unroll
    for (int i = 0; i < 2; ++i) {
      int r = ar + i * 32;
      int sw = ((ac ^ (r & 7)) << 3);
      int grow = row0 + r;
      uint4 va = make_uint4(0u, 0u, 0u, 0u);
      if (grow < M) {
        int arow = rowlist ? rowlist[grow] : grow;
        va = *(const uint4*)(A + (size_t)arow * K + kk + ac * 8);
      }
      *(uint4*)&As[r * 64 + sw] = va;
      int nrow = col0 + r;
      uint4 vb = *(const uint4*)(Bt + (size_t)nrow * K + kk + ac * 8);
      *(uint4*)&Bs[r * 64 + sw] = vb;
    }
    __syncthreads();
#pragma unroll
    for (int s = 0; s < 2; ++s) {
      int cc = s * 4 + quad;
      bf16x8 bF;
      {
        int r = wid * 16 + l16;
        bF = *(const bf16x8*)&Bs[r * 64 + ((cc ^ (r & 7)) << 3)];
      }
#pragma unroll
      for (int mi = 0; mi < 4; ++mi) {
        int r = mi * 16 + l16;
        bf16x8 aF = *(const bf16x8*)&As[r * 64 + ((cc ^ (r & 7)) << 3)];
        acc[mi] = __builtin_amdgcn_mfma_f32_16x16x32_bf16(aF, bF, acc[mi], 0, 0, 0);
      }
    }
  }
#pragma unroll
  for (int mi = 0; mi < 4; ++mi) {
#pragma unroll
    for (int i = 0; i < 4; ++i) {
      int r = row0 + mi * 16 + quad * 4 + i;
      int c = col0 + wid * 16 + l16;
      if (r < M) atomicAdd(&C[(size_t)r * Nc + c], acc[mi][i]);
    }
  }
}

// epilogue for split-K image FC: bias + bf16 + scatter
__global__ void k_sk_epi(const float* __restrict__ Cw, const float* __restrict__ bias,
                         const int* __restrict__ rmap, unsigned short* __restrict__ out,
                         int M, int Nc) {
  int i = blockIdx.x * blockDim.x + threadIdx.x;
  if (i >= M * Nc) return;
  int r = i / Nc, c = i - r * Nc;
  out[(size_t)rmap[r] * Nc + c] = f2bf(Cw[i] + bias[c]);
}

// ---------------- attention logits, bf16 f, H=4 D=256 ----------------
__global__ void k_elr4(const unsigned short* __restrict__ f, const float* __restrict__ al,
                       const float* __restrict__ ar, float* __restrict__ el,
                       float* __restrict__ er) {
  int v = blockIdx.x;
  int h = threadIdx.x >> 6, lane = threadIdx.x & 63;
  int d = lane * 4;
  ushort4 fv = *(const ushort4*)(f + (size_t)v * 1024 + h * 256 + d);
  float4 av = *(const float4*)(al + h * 256 + d);
  float4 rv = *(const float4*)(ar + h * 256 + d);
  float x0 = bf2f(fv.x), x1 = bf2f(fv.y), x2 = bf2f(fv.z), x3 = bf2f(fv.w);
  float a = x0 * av.x + x1 * av.y + x2 * av.z + x3 * av.w;
  float b = x0 * rv.x + x1 * rv.y + x2 * rv.z + x3 * rv.w;
#pragma unroll
  for (int off = 32; off; off >>= 1) {
    a += __shfl_down(a, off);
    b += __shfl_down(b, off);
  }
  if (lane == 0) { el[v * 4 + h] = a; er[v * 4 + h] = b; }
}

// ---------------- CSR build ----------------
__global__ void k_count(const int* __restrict__ dst, int* __restrict__ cnt, int E) {
  int e = blockIdx.x * blockDim.x + threadIdx.x;
  if (e < E) atomicAdd(&cnt[dst[e]], 1);
}

__global__ void k_scan(const int* __restrict__ deg, int* __restrict__ offs, int n) {
  __shared__ int part[1024];
  int tid = threadIdx.x;
  int per = (n + 1023) >> 10;
  int start = tid * per;
  int local = 0;
  for (int i = 0; i < per; ++i) { int idx = start + i; if (idx < n) local += deg[idx]; }
  part[tid] = local;
  __syncthreads();
  for (int off = 1; off < 1024; off <<= 1) {
    int add = (tid >= off) ? part[tid - off] : 0;
    __syncthreads();
    part[tid] += add;
    __syncthreads();
  }
  int run = (tid == 0) ? 0 : part[tid - 1];
  for (int i = 0; i < per; ++i) {
    int idx = start + i;
    if (idx < n) { offs[idx] = run; run += deg[idx]; }
  }
  if (tid == 1023) offs[n] = part[1023];
}

__global__ void k_fill(const int* __restrict__ src, const int* __restrict__ dst,
                       const int* __restrict__ offs, int* __restrict__ cur,
                       int* __restrict__ csr, int E) {
  int e = blockIdx.x * blockDim.x + threadIdx.x;
  if (e < E) {
    int d = dst[e];
    int slot = offs[d] + atomicAdd(&cur[d], 1);
    csr[slot] = src[e];
  }
}

// ---------------- per-edge softmax weights (H=4) ----------------
__global__ void k_alpha(const float* __restrict__ el, const float* __restrict__ er,
                        const int* __restrict__ offs, const int* __restrict__ csr,
                        float* __restrict__ alpha, float* __restrict__ zr) {
  int i = blockIdx.x * blockDim.x + threadIdx.x;
  if (i >= kN * 4) return;
  int v = i >> 2, h = i & 3;
  float erv = er[i];
  int e0 = offs[v], e1 = offs[v + 1];
  float m = -1e30f;
  for (int e = e0; e < e1; ++e) {
    float x = el[csr[e] * 4 + h] + erv;
    x = x > 0.f ? x : 0.2f * x;
    m = fmaxf(m, x);
  }
  float z = 0.f;
  for (int e = e0; e < e1; ++e) {
    float x = el[csr[e] * 4 + h] + erv;
    x = x > 0.f ? x : 0.2f * x;
    float w = expf(x - m);
    z += w;
    alpha[e * 4 + h] = w;
  }
  zr[i] = 1.f / z;
}

// ---------------- aggregation: bf16 gather with precomputed alpha ----------------
__global__ __launch_bounds__(256) void k_agg2(const unsigned short* __restrict__ f,
                                              const float* __restrict__ alpha,
                                              const float* __restrict__ zr,
                                              const int* __restrict__ offs,
                                              const int* __restrict__ csr,
                                              const float* __restrict__ bias,
                                              unsigned short* __restrict__ out) {
  int v = blockIdx.x;
  int tid = threadIdx.x;
  int h = tid >> 6;
  int d0 = tid * 4;
  int e0 = offs[v], e1 = offs[v + 1];
  float a0 = 0.f, a1 = 0.f, a2 = 0.f, a3 = 0.f;
  for (int e = e0; e < e1; ++e) {
    int s = csr[e];
    float w = alpha[e * 4 + h];
    ushort4 fv = *(const ushort4*)(f + (size_t)s * 1024 + d0);
    a0 += w * bf2f(fv.x);
    a1 += w * bf2f(fv.y);
    a2 += w * bf2f(fv.z);
    a3 += w * bf2f(fv.w);
  }
  float rz = zr[v * 4 + h];
  float4 bv = *(const float4*)(bias + d0);
  float o0 = a0 * rz + bv.x, o1 = a1 * rz + bv.y, o2 = a2 * rz + bv.z, o3 = a3 * rz + bv.w;
  o0 = o0 > 0.f ? o0 : expm1f(o0);
  o1 = o1 > 0.f ? o1 : expm1f(o1);
  o2 = o2 > 0.f ? o2 : expm1f(o2);
  o3 = o3 > 0.f ? o3 : expm1f(o3);
  ushort4 ov;
  ov.x = f2bf(o0); ov.y = f2bf(o1); ov.z = f2bf(o2); ov.w = f2bf(o3);
  *(ushort4*)(out + (size_t)v * 1024 + d0) = ov;
}

// ---------------- sparse gat2: build gathered row list for session-node edges ----------------
// info[0..3]=start, info[4..7]=cnt, info[8..11]=self row index
__global__ void k_rows2(const int* __restrict__ sid, const int* __restrict__ offs,
                        const int* __restrict__ csr, int* __restrict__ rowlist,
                        int* __restrict__ info) {
  if (threadIdx.x == 0 && blockIdx.x == 0) {
    int pos = 0;
    for (int bv = 0; bv < kB; ++bv) {
      int v = sid[bv];
      int e0 = offs[v], e1 = offs[v + 1];
      info[bv] = pos;
      info[4 + bv] = e1 - e0;
      int self = pos;
      for (int e = e0; e < e1 && pos < kCap; ++e) {
        int s = csr[e];
        if (s == v) self = pos;
        rowlist[pos++] = s;
      }
      info[8 + bv] = self;
    }
    for (int i = pos; i < kCap; ++i) rowlist[i] = 0;
  }
}

// el/er over compact fp32 rows [kCap][512]
__global__ void k_elr_c(const float* __restrict__ fc, const float* __restrict__ al,
                        const float* __restrict__ ar, float* __restrict__ el,
                        float* __restrict__ er) {
  int r = blockIdx.x;
  int lane = threadIdx.x;         // 64
  float a = 0.f, b = 0.f;
  for (int d = lane * 4; d < 512; d += 256) {
    float4 x = *(const float4*)(fc + (size_t)r * 512 + d);
    float4 av = *(const float4*)(al + d);
    float4 rv = *(const float4*)(ar + d);
    a += x.x * av.x + x.y * av.y + x.z * av.z + x.w * av.w;
    b += x.x * rv.x + x.y * rv.y + x.z * rv.z + x.w * rv.w;
  }
#pragma unroll
  for (int off = 32; off; off >>= 1) {
    a += __shfl_down(a, off);
    b += __shfl_down(b, off);
  }
  if (lane == 0) { el[r] = a; er[r] = b; }
}

// final aggregation over compact rows, output straight to d_out
__global__ __launch_bounds__(256) void k_agg_fin2(const float* __restrict__ fc,
                                                  const float* __restrict__ el,
                                                  const float* __restrict__ er,
                                                  const int* __restrict__ info,
                                                  const float* __restrict__ bias,
                                                  float* __restrict__ out) {
  int bv = blockIdx.x;
  int tid = threadIdx.x;
  int start = info[bv], cnt = info[4 + bv];
  float erv = er[info[8 + bv]];
  float m = -1e30f;
  for (int i = 0; i < cnt; ++i) {
    float x = el[start + i] + erv;
    x = x > 0.f ? x : 0.2f * x;
    m = fmaxf(m, x);
  }
  float z = 0.f, a0 = 0.f, a1 = 0.f;
  for (int i = 0; i < cnt; ++i) {
    int r = start + i;
    float x = el[r] + erv;
    x = x > 0.f ? x : 0.2f * x;
    float w = expf(x - m);
    z += w;
    a0 += w * fc[(size_t)r * 512 + tid];
    a1 += w * fc[(size_t)r * 512 + 256 + tid];
  }
  out[bv * 512 + tid] = a0 / z + bias[tid];
  out[bv * 512 + 256 + tid] = a1 / z + bias[256 + tid];
}

// ---------------- launcher ----------------
extern "C" void kernel_launch(void* const* d_in, const int* in_sizes, int n_in,
                              void* d_out, int out_size, void* d_ws, size_t ws_size,
                              hipStream_t stream) {
  const int*   all_words   = (const int*)d_in[0];
  const float* image_feats = (const float*)d_in[1];
  const int*   sentences   = (const int*)d_in[2];
  const float* sent_mask   = (const float*)d_in[3];
  const int*   utterances  = (const int*)d_in[4];
  const float* utt_mask    = (const float*)d_in[5];
  const int*   session_ids = (const int*)d_in[6];
  const int*   edge_src    = (const int*)d_in[7];
  const int*   edge_dst    = (const int*)d_in[8];
  const float* word_embed  = (const float*)d_in[9];
  const float* text_fc_w   = (const float*)d_in[10];
  const float* text_fc_b   = (const float*)d_in[11];
  const float* image_fc_w  = (const float*)d_in[12];
  const float* image_fc_b  = (const float*)d_in[13];
  const float* gat0_fc     = (const float*)d_in[14];
  const float* gat0_al     = (const float*)d_in[15];
  const float* gat0_ar     = (const float*)d_in[16];
  const float* gat0_b      = (const float*)d_in[17];
  const float* gat1_fc     = (const float*)d_in[18];
  const float* gat1_al     = (const float*)d_in[19];
  const float* gat1_ar     = (const float*)d_in[20];
  const float* gat1_b      = (const float*)d_in[21];
  const float* gat2_fc     = (const float*)d_in[22];
  const float* gat2_al     = (const float*)d_in[23];
  const float* gat2_ar     = (const float*)d_in[24];
  const float* gat2_b      = (const float*)d_in[25];

  const int E = in_sizes[7];

  char* base = (char*)d_ws;
  size_t off = 0;
  auto alloc = [&](size_t elems, size_t esz) -> void* {
    void* p = base + off;
    off += ((elems * esz + 255) / 256) * 256;
    return p;
  };
  unsigned short* Abf   = (unsigned short*)alloc((size_t)kN * kHid, 2);
  unsigned short* fbf   = (unsigned short*)alloc((size_t)kN * kHid, 2);
  unsigned short* txtbf = (unsigned short*)alloc((size_t)kTxtRows * kEmbPad, 2);
  unsigned short* imgbf = (unsigned short*)alloc((size_t)kB * kI * 2048, 2);
  unsigned short* wtTx  = (unsigned short*)alloc((size_t)kHid * kEmbPad, 2);
  unsigned short* wtIm  = (unsigned short*)alloc((size_t)kHid * 2048, 2);
  unsigned short* wtG0  = (unsigned short*)alloc((size_t)kHid * kHid, 2);
  unsigned short* wtG1  = (unsigned short*)alloc((size_t)kHid * kHid, 2);
  unsigned short* wtG2  = (unsigned short*)alloc((size_t)kOut * kHid, 2);
  float* Cimg   = (float*)alloc((size_t)kB * kI * kHid, 4);     // split-K image acc
  float* Cg2    = (float*)alloc((size_t)kCap * kOut, 4);        // split-K gat2 acc
  float* sentb  = (float*)alloc((size_t)kB * kS * kEmb, 4);
  float* uttb   = (float*)alloc((size_t)kB * kU * kEmb, 4);
  float* sessb  = (float*)alloc((size_t)kB * kEmb, 4);
  float* el     = (float*)alloc((size_t)kN * 4, 4);
  float* er     = (float*)alloc((size_t)kN * 4, 4);
  float* alphab = (float*)alloc((size_t)E * 4, 4);
  float* zrb    = (float*)alloc((size_t)kN * 4, 4);
  int*   offs   = (int*)alloc(kN + 1, 4);
  int*   cnt    = (int*)alloc(kN, 4);
  int*   csr    = (int*)alloc(E, 4);
  int*   rmt    = (int*)alloc(kTxtRows, 4);
  int*   rmi    = (int*)alloc(kB * kI, 4);
  int*   rowl   = (int*)alloc(kCap, 4);
  int*   info   = (int*)alloc(16, 4);
  (void)ws_size; (void)n_in; (void)out_size;

  // --- feature construction ---
  k_sent<<<kB * kS, 128, 0, stream>>>(sentences, sent_mask, word_embed, sentb);
  k_utt<<<kB * kU, 128, 0, stream>>>(utterances, utt_mask, sentb, uttb);
  k_sess<<<kB, 128, 0, stream>>>(uttb, sessb);
  k_txtgather<<<kTxtRows, 128, 0, stream>>>(all_words, word_embed, sentb, uttb, sessb, txtbf);
  k_rowmap<<<(kTxtRows + 255) / 256, 256, 0, stream>>>(rmt, rmi);
  k_f2bf<<<(kB * kI * 2048 + 255) / 256, 256, 0, stream>>>(image_feats, imgbf, kB * kI * 2048);

  // --- weight transpose+convert ---
  dim3 tb(32, 8);
  k_wtrans<<<dim3(kHid / 32, kEmbPad / 32), tb, 0, stream>>>(text_fc_w, wtTx, kEmb, kHid, kEmbPad);
  k_wtrans<<<dim3(kHid / 32, 2048 / 32),    tb, 0, stream>>>(image_fc_w, wtIm, 2048, kHid, 2048);
  k_wtrans<<<dim3(kHid / 32, kHid / 32),    tb, 0, stream>>>(gat0_fc, wtG0, kHid, kHid, kHid);
  k_wtrans<<<dim3(kHid / 32, kHid / 32),    tb, 0, stream>>>(gat1_fc, wtG1, kHid, kHid, kHid);
  k_wtrans<<<dim3(kOut / 32, kHid / 32),    tb, 0, stream>>>(gat2_fc, wtG2, kHid, kOut, kHid);

  // --- CSR build ---
  hipMemsetAsync(cnt, 0, kN * sizeof(int), stream);
  k_count<<<(E + 255) / 256, 256, 0, stream>>>(edge_dst, cnt, E);
  k_scan<<<1, 1024, 0, stream>>>(cnt, offs, kN);
  hipMemsetAsync(cnt, 0, kN * sizeof(int), stream);
  k_fill<<<(E + 255) / 256, 256, 0, stream>>>(edge_src, edge_dst, offs, cnt, csr, E);

  // --- text FC (128-tile MFMA, scatter bf16) ---
  k_mm<true><<<dim3(kHid / 128, (kTxtRows + 127) / 128), 256, 0, stream>>>(
      txtbf, wtTx, text_fc_b, rmt, Abf, kTxtRows, kEmbPad, kHid);

  // --- image FC via split-K (M=256, K=2048, 4 splits of 512) ---
  hipMemsetAsync(Cimg, 0, (size_t)kB * kI * kHid * sizeof(float), stream);
  k_mm_sk<<<dim3(kHid / 64, kB * kI / 64, 4), 256, 0, stream>>>(
      imgbf, wtIm, nullptr, Cimg, kB * kI, 2048, kHid, 512);
  k_sk_epi<<<(kB * kI * kHid + 255) / 256, 256, 0, stream>>>(
      Cimg, image_fc_b, rmi, Abf, kB * kI, kHid);

  // --- GAT layer 0 ---
  k_mm<true><<<dim3(kHid / 128, (kN + 127) / 128), 256, 0, stream>>>(
      Abf, wtG0, nullptr, nullptr, fbf, kN, kHid, kHid);
  k_elr4<<<kN, 256, 0, stream>>>(fbf, gat0_al, gat0_ar, el, er);
  k_alpha<<<(kN * 4 + 255) / 256, 256, 0, stream>>>(el, er, offs, csr, alphab, zrb);
  k_agg2<<<kN, 256, 0, stream>>>(fbf, alphab, zrb, offs, csr, gat0_b, Abf);

  // --- GAT layer 1 ---
  k_mm<true><<<dim3(kHid / 128, (kN + 127) / 128), 256, 0, stream>>>(
      Abf, wtG1, nullptr, nullptr, fbf, kN, kHid, kHid);
  k_elr4<<<kN, 256, 0, stream>>>(fbf, gat1_al, gat1_ar, el, er);
  k_alpha<<<(kN * 4 + 255) / 256, 256, 0, stream>>>(el, er, offs, csr, alphab, zrb);
  k_agg2<<<kN, 256, 0, stream>>>(fbf, alphab, zrb, offs, csr, gat1_b, Abf);

  // --- GAT layer 2, sparse: only rows feeding the 4 session nodes ---
  k_rows2<<<1, 64, 0, stream>>>(session_ids, offs, csr, rowl, info);
  hipMemsetAsync(Cg2, 0, (size_t)kCap * kOut * sizeof(float), stream);
  k_mm_sk<<<dim3(kOut / 64, kCap / 64, 4), 256, 0, stream>>>(
      Abf, wtG2, rowl, Cg2, kCap, kHid, kOut, 256);
  k_elr_c<<<kCap, 64, 0, stream>>>(Cg2, gat2_al, gat2_ar, el, er);
  k_agg_fin2<<<kB, 256, 0, stream>>>(Cg2, el, er, info, gat2_b, (float*)d_out);
}